// Round 2
// baseline (1804.038 us; speedup 1.0000x reference)
//
#include <hip/hip_runtime.h>
#include <hip/hip_bf16.h>

// ---------------------------------------------------------------------------
// ToMe16 token merge (6 rounds) + 2-layer MLP, MI355X gfx950.
// All merge math in fp32 with deterministic orders to match the numpy ref's
// discrete decisions (argmax / stable argsort). MLP fp32. Output fp32.
// ---------------------------------------------------------------------------

// metric = mean over 16 heads of x (p,16,64), then L2-normalize rows.
// One wave (64 lanes) per row; lane d owns dim d.
__global__ __launch_bounds__(256) void metric_kernel(const float* __restrict__ x,
                                                     float* __restrict__ mnorm, int p)
{
    int row  = blockIdx.x * 4 + (threadIdx.x >> 6);
    int lane = threadIdx.x & 63;
    if (row >= p) return;
    const float* xr = x + (size_t)row * 1024;
    float m = 0.f;
#pragma unroll
    for (int h = 0; h < 16; ++h) m += xr[h * 64 + lane];
    m *= 0.0625f;                       // /16 exact
    float s = m * m;
#pragma unroll
    for (int off = 32; off > 0; off >>= 1) s += __shfl_xor(s, off, 64);
    mnorm[(size_t)row * 64 + lane] = m / sqrtf(s);
}

// scores[i][j] = dot(a_i, b_j), a = even metric rows, b = odd metric rows.
// Thread owns row i (a_i in 64 VGPRs); j-tile of 128 odd rows staged in LDS
// (broadcast reads, conflict-free). Tracks (max, first-argmax) per row over a
// j-chunk; partials combined by reduce_kernel (ascending js => first-occurrence
// tie-break preserved, matching jnp.argmax).
__global__ __launch_bounds__(256) void scores_kernel(const float* __restrict__ metric,
                                                     float* __restrict__ pmax,
                                                     int* __restrict__ pidx,
                                                     int P2, int jchunk, int JS)
{
    __shared__ float Bs[128][64];
    int i  = blockIdx.x * 256 + threadIdx.x;
    int js = blockIdx.y;
    int j0 = js * jchunk;
    int j1 = j0 + jchunk; if (j1 > P2) j1 = P2;
    bool rowok = (i < P2);

    float a[64];
    if (rowok) {
        const float4* ar = reinterpret_cast<const float4*>(metric + (size_t)(2 * i) * 64);
#pragma unroll
        for (int u = 0; u < 16; ++u) {
            float4 v = ar[u];
            a[4*u] = v.x; a[4*u+1] = v.y; a[4*u+2] = v.z; a[4*u+3] = v.w;
        }
    }

    float best = -3.0e38f; int bj = 0;
    for (int jt = j0; jt < j1; jt += 128) {
        int jn = j1 - jt; if (jn > 128) jn = 128;
        __syncthreads();
        for (int t = threadIdx.x; t < jn * 64; t += 256) {
            int jj = t >> 6, d = t & 63;
            Bs[jj][d] = metric[(size_t)(2 * (jt + jj) + 1) * 64 + d];
        }
        __syncthreads();
        if (rowok) {
            for (int jj = 0; jj < jn; ++jj) {
                float s = 0.f;
#pragma unroll
                for (int d = 0; d < 64; ++d) s = fmaf(a[d], Bs[jj][d], s);
                if (s > best) { best = s; bj = jt + jj; }   // strict > : first max
            }
        }
    }
    if (rowok) { pmax[(size_t)i * JS + js] = best; pidx[(size_t)i * JS + js] = bj; }
}

__global__ __launch_bounds__(256) void reduce_kernel(const float* __restrict__ pmax,
                                                     const int* __restrict__ pidx,
                                                     float* __restrict__ nmax,
                                                     int* __restrict__ nidx,
                                                     int P2, int JS)
{
    int i = blockIdx.x * 256 + threadIdx.x;
    if (i >= P2) return;
    float best = -3.3e38f; int bj = 0;
    for (int js = 0; js < JS; ++js) {
        float v = pmax[(size_t)i * JS + js];
        if (v > best) { best = v; bj = pidx[(size_t)i * JS + js]; }
    }
    nmax[i] = best; nidx[i] = bj;
}

// Rounds 1-5 (r == p/2): out[j] = (x_odd[j]*s_odd + sum_{i: nidx[i]==j} x_even[i]*s_even[i]) / newsize
// Duplicate accumulation ordered by (node_max desc, idx asc) == np.add.at's src order.
__global__ __launch_bounds__(256) void merge_kernel(const float* __restrict__ x,
                                                    const float* __restrict__ size_in,
                                                    const int* __restrict__ nidx,
                                                    const float* __restrict__ nmax,
                                                    float* __restrict__ xout,
                                                    float* __restrict__ size_out, int P2)
{
    int j = blockIdx.x;
    __shared__ int   list[128];
    __shared__ int   cnt_s;
    __shared__ float ns_s;
    if (threadIdx.x == 0) cnt_s = 0;
    __syncthreads();
    for (int i = threadIdx.x; i < P2; i += 256) {
        if (nidx[i] == j) { int p = atomicAdd(&cnt_s, 1); if (p < 128) list[p] = i; }
    }
    __syncthreads();
    int total = cnt_s;
    bool over = (total > 128);                 // pathological hub fallback
    if (threadIdx.x == 0) {
        float ns = size_in ? size_in[2 * j + 1] : 1.0f;
        if (!over) {
            // insertion sort by (nmax desc, idx asc) — deterministic
            for (int u = 1; u < total; ++u) {
                int v = list[u]; float kv = nmax[v]; int w = u - 1;
                while (w >= 0) {
                    int lw = list[w]; float kw = nmax[lw];
                    if (kw < kv || (kw == kv && lw > v)) { list[w + 1] = lw; --w; }
                    else break;
                }
                list[w + 1] = v;
            }
            for (int u = 0; u < total; ++u) ns += size_in ? size_in[2 * list[u]] : 1.0f;
        } else {
            for (int i = 0; i < P2; ++i)
                if (nidx[i] == j) ns += size_in ? size_in[2 * i] : 1.0f;
        }
        ns_s = ns;
        size_out[j] = ns;
    }
    __syncthreads();
    float ns   = ns_s;
    float sodd = size_in ? size_in[2 * j + 1] : 1.0f;
    for (int c = threadIdx.x; c < 1024; c += 256) {
        float acc = x[(size_t)(2 * j + 1) * 1024 + c] * sodd;
        if (!over) {
            for (int u = 0; u < total; ++u) {
                int i2 = list[u];
                float si = size_in ? size_in[2 * i2] : 1.0f;
                acc += x[(size_t)(2 * i2) * 1024 + c] * si;
            }
        } else {
            for (int i2 = 0; i2 < P2; ++i2) {
                if (nidx[i2] == j) {
                    float si = size_in ? size_in[2 * i2] : 1.0f;
                    acc += x[(size_t)(2 * i2) * 1024 + c] * si;
                }
            }
        }
        xout[(size_t)j * 1024 + c] = acc / ns;
    }
}

// Round 6: stable descending argsort of node_max via O(n^2) rank counting.
// rank_i = #{k : max_k > max_i  or (max_k == max_i and k < i)}  (== jnp.argsort(-nm))
__global__ __launch_bounds__(512) void rank_kernel(const float* __restrict__ nmax,
                                                   int* __restrict__ edgeidx, int n)
{
    int i = threadIdx.x;
    if (i >= n) return;
    float v = nmax[i];
    int r = 0;
    for (int k = 0; k < n; ++k) {
        float u = nmax[k];
        if (u > v || (u == v && k < i)) ++r;
    }
    edgeidx[r] = i;
}

// Round 6 unmerged tokens: out rows 0..n_unm-1 in edge order; value (x*s)/s (two
// roundings, matching the reference's multiply-then-divide).
__global__ __launch_bounds__(256) void unm_kernel(const float* __restrict__ x,
                                                  const float* __restrict__ size_in,
                                                  const int* __restrict__ edgeidx,
                                                  float* __restrict__ xout, int r)
{
    int t = blockIdx.x;
    int i = edgeidx[r + t];
    float s = size_in[2 * i];
    for (int c = threadIdx.x; c < 1024; c += 256)
        xout[(size_t)t * 1024 + c] = (x[(size_t)(2 * i) * 1024 + c] * s) / s;
}

// Round 6 dst tokens: scan the 64-entry src list in edge order (== np.add.at order).
__global__ __launch_bounds__(256) void dst6_kernel(const float* __restrict__ x,
                                                   const float* __restrict__ size_in,
                                                   const int* __restrict__ edgeidx,
                                                   const int* __restrict__ nidx,
                                                   float* __restrict__ xout,
                                                   int r, int out_off)
{
    int j = blockIdx.x;
    __shared__ int   list[64];
    __shared__ int   cnt_s;
    __shared__ float ns_s;
    if (threadIdx.x == 0) {
        int n = 0; float ns = size_in[2 * j + 1];
        for (int m = 0; m < r; ++m) {
            int i2 = edgeidx[m];
            if (nidx[i2] == j) { list[n++] = i2; ns += size_in[2 * i2]; }
        }
        cnt_s = n; ns_s = ns;
    }
    __syncthreads();
    int n = cnt_s; float ns = ns_s;
    float sodd = size_in[2 * j + 1];
    for (int c = threadIdx.x; c < 1024; c += 256) {
        float acc = x[(size_t)(2 * j + 1) * 1024 + c] * sodd;
        for (int u = 0; u < n; ++u) {
            int i2 = list[u];
            acc += x[(size_t)(2 * i2) * 1024 + c] * size_in[2 * i2];
        }
        xout[(size_t)(out_off + j) * 1024 + c] = acc / ns;
    }
}

// Simple fp32 tiled GEMM: C = act(A@B + bias). 64x64 tile, 256 threads, 4x4 micro.
// ACT: 1 = exact GELU. OUTBF16: 1 = store bf16 (unused now; output is fp32).
template <int ACT, int OUTBF16>
__global__ __launch_bounds__(256) void gemm_kernel(const float* __restrict__ A,
                                                   const float* __restrict__ B,
                                                   const float* __restrict__ bias,
                                                   void* __restrict__ Cout,
                                                   int M, int N, int K)
{
    __shared__ float As[16][65];
    __shared__ float Bs[16][65];
    int bj = blockIdx.x * 64;
    int bi = blockIdx.y * 64;
    int tx = threadIdx.x & 15, ty = threadIdx.x >> 4;
    float acc[4][4] = {};
    for (int k0 = 0; k0 < K; k0 += 16) {
        __syncthreads();
        for (int t = threadIdx.x; t < 64 * 16; t += 256) {
            int ii = t >> 4, kk = t & 15;
            As[kk][ii] = A[(size_t)(bi + ii) * K + k0 + kk];
        }
        for (int t = threadIdx.x; t < 16 * 64; t += 256) {
            int kk = t >> 6, jj = t & 63;
            Bs[kk][jj] = B[(size_t)(k0 + kk) * N + bj + jj];
        }
        __syncthreads();
#pragma unroll
        for (int kk = 0; kk < 16; ++kk) {
            float av[4], bv[4];
#pragma unroll
            for (int u = 0; u < 4; ++u) av[u] = As[kk][ty * 4 + u];
#pragma unroll
            for (int u = 0; u < 4; ++u) bv[u] = Bs[kk][tx * 4 + u];
#pragma unroll
            for (int a = 0; a < 4; ++a)
#pragma unroll
                for (int b = 0; b < 4; ++b)
                    acc[a][b] = fmaf(av[a], bv[b], acc[a][b]);
        }
    }
    for (int a = 0; a < 4; ++a) {
        int i = bi + ty * 4 + a;
        if (i >= M) continue;
        for (int b = 0; b < 4; ++b) {
            int j = bj + tx * 4 + b;
            if (j >= N) continue;
            float v = acc[a][b] + bias[j];
            if (ACT) v = 0.5f * v * (1.0f + erff(v * 0.70710678118654752440f));
            if (OUTBF16)
                ((__hip_bfloat16*)Cout)[(size_t)i * N + j] = __float2bfloat16(v);
            else
                ((float*)Cout)[(size_t)i * N + j] = v;
        }
    }
}

extern "C" void kernel_launch(void* const* d_in, const int* in_sizes, int n_in,
                              void* d_out, int out_size, void* d_ws, size_t ws_size,
                              hipStream_t stream)
{
    const float* x_in = (const float*)d_in[0];   // (32,576,1024) == (18432,1024)
    const float* W1   = (const float*)d_in[1];   // (1024,4096)
    const float* b1   = (const float*)d_in[2];   // (4096)
    const float* W2   = (const float*)d_in[3];   // (4096,4096)
    const float* b2   = (const float*)d_in[4];   // (4096)
    float* out = (float*)d_out;                  // (512,4096) fp32

    // ---- workspace carve (256B aligned blocks) -------------------------------
    char* w = (char*)d_ws;
    float* xA     = (float*)w; w += (size_t)9216 * 1024 * 4;   // 37.75 MB
    float* xB     = (float*)w; w += (size_t)9216 * 1024 * 4;   // 37.75 MB
    float* metric = (float*)w; w += (size_t)18432 * 64 * 4;    //  4.72 MB
    float* sizeA  = (float*)w; w += 9216 * 4;
    float* sizeB  = (float*)w; w += 9216 * 4;
    float* nmax   = (float*)w; w += 9216 * 4;
    int*   nidx   = (int*)w;   w += 9216 * 4;
    float* pmax   = (float*)w; w += (size_t)9216 * 64 * 4;     //  2.36 MB
    int*   pidx   = (int*)w;   w += (size_t)9216 * 64 * 4;     //  2.36 MB
    int*   edgeidx= (int*)w;   w += 2048;
    float* h      = xA;   // xA is free after round 6 (rounds: in xA -> out xB)

    const int pcount[6] = {18432, 9216, 4608, 2304, 1152, 576};
    float* xbufs[2] = {xA, xB};
    float* sbufs[2] = {sizeA, sizeB};

    const float* xcur = x_in;
    const float* scur = nullptr;

    for (int rd = 0; rd < 6; ++rd) {
        int p  = pcount[rd];
        int P2 = p / 2;
        float* xout = xbufs[rd & 1];
        float* sout = sbufs[rd & 1];

        metric_kernel<<<dim3((p + 3) / 4), dim3(256), 0, stream>>>(xcur, metric, p);

        int iblocks = (P2 + 255) / 256;
        int JS = 1024 / iblocks;
        if (JS > 64) JS = 64;
        if (JS < 1)  JS = 1;
        int jchunk = (P2 + JS - 1) / JS;
        scores_kernel<<<dim3(iblocks, JS), dim3(256), 0, stream>>>(metric, pmax, pidx,
                                                                   P2, jchunk, JS);
        reduce_kernel<<<dim3(iblocks), dim3(256), 0, stream>>>(pmax, pidx, nmax, nidx,
                                                               P2, JS);
        if (rd < 5) {
            merge_kernel<<<dim3(P2), dim3(256), 0, stream>>>(xcur, scur, nidx, nmax,
                                                             xout, sout, P2);
        } else {
            // r = 64, unm = 224, dst = 288, out = 512
            rank_kernel<<<dim3(1), dim3(512), 0, stream>>>(nmax, edgeidx, P2);
            unm_kernel<<<dim3(P2 - 64), dim3(256), 0, stream>>>(xcur, scur, edgeidx,
                                                                xout, 64);
            dst6_kernel<<<dim3(P2), dim3(256), 0, stream>>>(xcur, scur, edgeidx, nidx,
                                                            xout, 64, P2 - 64);
        }
        xcur = xout;
        scur = sout;
    }

    // ---- MLP: h = gelu(x@W1+b1); out = h@W2+b2 (fp32) ------------------------
    gemm_kernel<1, 0><<<dim3(4096 / 64, 512 / 64), dim3(256), 0, stream>>>(
        xcur, W1, b1, (void*)h, 512, 4096, 1024);
    gemm_kernel<0, 0><<<dim3(4096 / 64, 512 / 64), dim3(256), 0, stream>>>(
        h, W2, b2, (void*)out, 512, 4096, 4096);
}

// Round 3
// 885.155 us; speedup vs baseline: 2.0381x; 2.0381x over previous
//
#include <hip/hip_runtime.h>
#include <hip/hip_bf16.h>

// ---------------------------------------------------------------------------
// ToMe16 token merge (6 rounds, fp32, numpy-exact decision order) +
// bf16-MFMA 2-layer MLP.  MI355X gfx950.
// ---------------------------------------------------------------------------

typedef __attribute__((ext_vector_type(8))) short bf16x8;
typedef __attribute__((ext_vector_type(4))) float f32x4;

// metric = mean over 16 heads of x (p,16,64), then L2-normalize rows.
__global__ __launch_bounds__(256) void metric_kernel(const float* __restrict__ x,
                                                     float* __restrict__ mnorm, int p)
{
    int row  = blockIdx.x * 4 + (threadIdx.x >> 6);
    int lane = threadIdx.x & 63;
    if (row >= p) return;
    const float* xr = x + (size_t)row * 1024;
    float m = 0.f;
#pragma unroll
    for (int h = 0; h < 16; ++h) m += xr[h * 64 + lane];
    m *= 0.0625f;
    float s = m * m;
#pragma unroll
    for (int off = 32; off > 0; off >>= 1) s += __shfl_xor(s, off, 64);
    mnorm[(size_t)row * 64 + lane] = m / sqrtf(s);
}

// scores[i][j] = dot(a_i, b_j) over d=0..63 (scalar fmaf, ascending d — same FP
// order as the previously-passing version => identical argmax decisions).
// 64x64 tile, 4x4 micro per thread, [d][i]-layout LDS (pad 68 => fp32 float4
// aligned, transpose-write ~8-way only on 16 store instrs). Block-local
// (max, first-idx) per row -> pmax[jb*P2 + i].
__global__ __launch_bounds__(256) void scores_kernel(const float* __restrict__ metric,
                                                     float* __restrict__ pmax,
                                                     int* __restrict__ pidx, int P2)
{
    __shared__ float As[64 * 68];
    __shared__ float Bs[64 * 68];
    const int t = threadIdx.x;
    const int i0 = blockIdx.x * 64, j0 = blockIdx.y * 64;

#pragma unroll
    for (int u = 0; u < 16; ++u) {
        int idx = u * 256 + t;
        int d = idx & 63, i = idx >> 6;      // per-u: 4 i values, d coalesced
        int gi = i0 + i;
        As[d * 68 + i] = (gi < P2) ? metric[(size_t)(2 * gi) * 64 + d] : 0.f;
        int gj = j0 + i;
        Bs[d * 68 + i] = (gj < P2) ? metric[(size_t)(2 * gj + 1) * 64 + d] : 0.f;
    }
    __syncthreads();

    const int tx = t & 15, ty = t >> 4;
    float acc[4][4];
#pragma unroll
    for (int u = 0; u < 4; ++u)
#pragma unroll
        for (int v = 0; v < 4; ++v) acc[u][v] = 0.f;

    for (int d = 0; d < 64; ++d) {
        float4 av = *reinterpret_cast<const float4*>(&As[d * 68 + ty * 4]);
        float4 bv = *reinterpret_cast<const float4*>(&Bs[d * 68 + tx * 4]);
        float a_[4] = {av.x, av.y, av.z, av.w};
        float b_[4] = {bv.x, bv.y, bv.z, bv.w};
#pragma unroll
        for (int u = 0; u < 4; ++u)
#pragma unroll
            for (int v = 0; v < 4; ++v)
                acc[u][v] = fmaf(a_[u], b_[v], acc[u][v]);
    }

#pragma unroll
    for (int u = 0; u < 4; ++u) {
        float best = -3.0e38f; int bj = 0x7fffffff;
#pragma unroll
        for (int v = 0; v < 4; ++v) {
            int j = j0 + tx * 4 + v;
            if (j < P2 && acc[u][v] > best) { best = acc[u][v]; bj = j; }
        }
        // combine across the 16 tx-lanes (same wave); tie -> smaller j (= first)
#pragma unroll
        for (int off = 1; off < 16; off <<= 1) {
            float ob = __shfl_xor(best, off, 64);
            int   oj = __shfl_xor(bj,   off, 64);
            if (ob > best || (ob == best && oj < bj)) { best = ob; bj = oj; }
        }
        if (tx == 0) {
            int gi = i0 + ty * 4 + u;
            if (gi < P2) {
                pmax[(size_t)blockIdx.y * P2 + gi] = best;
                pidx[(size_t)blockIdx.y * P2 + gi] = bj;
            }
        }
    }
}

__global__ __launch_bounds__(256) void reduce_kernel(const float* __restrict__ pmax,
                                                     const int* __restrict__ pidx,
                                                     float* __restrict__ nmax,
                                                     int* __restrict__ nidx,
                                                     int P2, int JS)
{
    int i = blockIdx.x * 256 + threadIdx.x;
    if (i >= P2) return;
    float best = -3.3e38f; int bj = 0;
    for (int js = 0; js < JS; ++js) {
        float v = pmax[(size_t)js * P2 + i];
        if (v > best) { best = v; bj = pidx[(size_t)js * P2 + i]; }
    }
    nmax[i] = best; nidx[i] = bj;
}

// Rounds 1-5 (r == p/2). Duplicate accumulation ordered by (node_max desc,
// idx asc) == np.add.at's source order.
__global__ __launch_bounds__(256) void merge_kernel(const float* __restrict__ x,
                                                    const float* __restrict__ size_in,
                                                    const int* __restrict__ nidx,
                                                    const float* __restrict__ nmax,
                                                    float* __restrict__ xout,
                                                    float* __restrict__ size_out, int P2)
{
    int j = blockIdx.x;
    __shared__ int   list[128];
    __shared__ int   cnt_s;
    __shared__ float ns_s;
    if (threadIdx.x == 0) cnt_s = 0;
    __syncthreads();
    for (int i = threadIdx.x; i < P2; i += 256) {
        if (nidx[i] == j) { int p = atomicAdd(&cnt_s, 1); if (p < 128) list[p] = i; }
    }
    __syncthreads();
    int total = cnt_s;
    bool over = (total > 128);
    if (threadIdx.x == 0) {
        float ns = size_in ? size_in[2 * j + 1] : 1.0f;
        if (!over) {
            for (int u = 1; u < total; ++u) {
                int v = list[u]; float kv = nmax[v]; int w = u - 1;
                while (w >= 0) {
                    int lw = list[w]; float kw = nmax[lw];
                    if (kw < kv || (kw == kv && lw > v)) { list[w + 1] = lw; --w; }
                    else break;
                }
                list[w + 1] = v;
            }
            for (int u = 0; u < total; ++u) ns += size_in ? size_in[2 * list[u]] : 1.0f;
        } else {
            for (int i = 0; i < P2; ++i)
                if (nidx[i] == j) ns += size_in ? size_in[2 * i] : 1.0f;
        }
        ns_s = ns;
        size_out[j] = ns;
    }
    __syncthreads();
    float ns   = ns_s;
    float sodd = size_in ? size_in[2 * j + 1] : 1.0f;
    for (int c = threadIdx.x; c < 1024; c += 256) {
        float acc = x[(size_t)(2 * j + 1) * 1024 + c] * sodd;
        if (!over) {
            for (int u = 0; u < total; ++u) {
                int i2 = list[u];
                float si = size_in ? size_in[2 * i2] : 1.0f;
                acc += x[(size_t)(2 * i2) * 1024 + c] * si;
            }
        } else {
            for (int i2 = 0; i2 < P2; ++i2) {
                if (nidx[i2] == j) {
                    float si = size_in ? size_in[2 * i2] : 1.0f;
                    acc += x[(size_t)(2 * i2) * 1024 + c] * si;
                }
            }
        }
        xout[(size_t)j * 1024 + c] = acc / ns;
    }
}

// Round 6 helpers (stable descending argsort, unm gather, dst scatter).
__global__ __launch_bounds__(512) void rank_kernel(const float* __restrict__ nmax,
                                                   int* __restrict__ edgeidx, int n)
{
    int i = threadIdx.x;
    if (i >= n) return;
    float v = nmax[i];
    int r = 0;
    for (int k = 0; k < n; ++k) {
        float u = nmax[k];
        if (u > v || (u == v && k < i)) ++r;
    }
    edgeidx[r] = i;
}

__global__ __launch_bounds__(256) void unm_kernel(const float* __restrict__ x,
                                                  const float* __restrict__ size_in,
                                                  const int* __restrict__ edgeidx,
                                                  float* __restrict__ xout, int r)
{
    int tb = blockIdx.x;
    int i = edgeidx[r + tb];
    float s = size_in[2 * i];
    for (int c = threadIdx.x; c < 1024; c += 256)
        xout[(size_t)tb * 1024 + c] = (x[(size_t)(2 * i) * 1024 + c] * s) / s;
}

__global__ __launch_bounds__(256) void dst6_kernel(const float* __restrict__ x,
                                                   const float* __restrict__ size_in,
                                                   const int* __restrict__ edgeidx,
                                                   const int* __restrict__ nidx,
                                                   float* __restrict__ xout,
                                                   int r, int out_off)
{
    int j = blockIdx.x;
    __shared__ int   list[64];
    __shared__ int   cnt_s;
    __shared__ float ns_s;
    if (threadIdx.x == 0) {
        int n = 0; float ns = size_in[2 * j + 1];
        for (int m = 0; m < r; ++m) {
            int i2 = edgeidx[m];
            if (nidx[i2] == j) { list[n++] = i2; ns += size_in[2 * i2]; }
        }
        cnt_s = n; ns_s = ns;
    }
    __syncthreads();
    int n = cnt_s; float ns = ns_s;
    float sodd = size_in[2 * j + 1];
    for (int c = threadIdx.x; c < 1024; c += 256) {
        float acc = x[(size_t)(2 * j + 1) * 1024 + c] * sodd;
        for (int u = 0; u < n; ++u) {
            int i2 = list[u];
            acc += x[(size_t)(2 * i2) * 1024 + c] * size_in[2 * i2];
        }
        xout[(size_t)(out_off + j) * 1024 + c] = acc / ns;
    }
}

// ---- bf16 cast / transpose-cast ------------------------------------------
__global__ __launch_bounds__(256) void castx_kernel(const float* __restrict__ in,
                                                    __hip_bfloat16* __restrict__ out, int n)
{
    int i = blockIdx.x * 256 + threadIdx.x;
    if (i < n) out[i] = __float2bfloat16(in[i]);
}

// in[K][N] fp32 -> outT[N][K] bf16 (32x32 LDS tile transpose)
__global__ __launch_bounds__(256) void transcast_kernel(const float* __restrict__ in,
                                                        __hip_bfloat16* __restrict__ outT,
                                                        int K, int N)
{
    __shared__ float tile[32][33];
    int n0 = blockIdx.x * 32, k0 = blockIdx.y * 32;
    int tx = threadIdx.x & 31, ty = threadIdx.x >> 5;   // 8 rows of 32
#pragma unroll
    for (int u = 0; u < 4; ++u) {
        int k = k0 + ty + u * 8;
        tile[ty + u * 8][tx] = in[(size_t)k * N + n0 + tx];
    }
    __syncthreads();
#pragma unroll
    for (int u = 0; u < 4; ++u) {
        int n = n0 + ty + u * 8;
        outT[(size_t)n * K + k0 + tx] = __float2bfloat16(tile[tx][ty + u * 8]);
    }
}

// ---- bf16 MFMA GEMM: C = act(A@B^T + bias) -------------------------------
// A[M][K] bf16, Bt[N][K] bf16. 64x64 tile, BK=64, 4 waves (2x2), each wave
// 32x32 (2x2 frags of 16x16x32). XOR-swizzled LDS (chunk ^= row&7) kills the
// row-stride-128B 16-way bank conflict on ds_read_b128.
template <int ACT, int OUTBF16>
__global__ __launch_bounds__(256) void mfma_gemm_kernel(
    const unsigned short* __restrict__ A,
    const unsigned short* __restrict__ Bt,
    const float* __restrict__ bias,
    void* __restrict__ Cout, int M, int N, int K)
{
    __shared__ unsigned short As[64 * 64];
    __shared__ unsigned short Bs[64 * 64];
    const int t = threadIdx.x;
    const int lane = t & 63, wave = t >> 6;
    const int wm = wave >> 1, wn = wave & 1;
    const int bi = blockIdx.y * 64, bj = blockIdx.x * 64;
    const int l15 = lane & 15, lg = lane >> 4;

    f32x4 acc[2][2];
#pragma unroll
    for (int m = 0; m < 2; ++m)
#pragma unroll
        for (int n = 0; n < 2; ++n)
#pragma unroll
            for (int r = 0; r < 4; ++r) acc[m][n][r] = 0.f;

    for (int k0 = 0; k0 < K; k0 += 64) {
        __syncthreads();
#pragma unroll
        for (int q = 0; q < 2; ++q) {
            int c = q * 256 + t;          // 16B chunk id, 512 per tile
            int row = c >> 3, cc = c & 7;
            int sc = cc ^ (row & 7);      // swizzle applied on the LDS slot
            *reinterpret_cast<int4*>(&As[row * 64 + sc * 8]) =
                *reinterpret_cast<const int4*>(A + (size_t)(bi + row) * K + k0 + cc * 8);
            *reinterpret_cast<int4*>(&Bs[row * 64 + sc * 8]) =
                *reinterpret_cast<const int4*>(Bt + (size_t)(bj + row) * K + k0 + cc * 8);
        }
        __syncthreads();
#pragma unroll
        for (int kc = 0; kc < 2; ++kc) {
            bf16x8 af[2], bfr[2];
#pragma unroll
            for (int m = 0; m < 2; ++m) {
                int row = wm * 32 + m * 16 + l15;
                int c = kc * 4 + lg;
                int sc = c ^ (row & 7);
                af[m] = *reinterpret_cast<const bf16x8*>(&As[row * 64 + sc * 8]);
            }
#pragma unroll
            for (int n = 0; n < 2; ++n) {
                int col = wn * 32 + n * 16 + l15;
                int c = kc * 4 + lg;
                int sc = c ^ (col & 7);
                bfr[n] = *reinterpret_cast<const bf16x8*>(&Bs[col * 64 + sc * 8]);
            }
#pragma unroll
            for (int m = 0; m < 2; ++m)
#pragma unroll
                for (int n = 0; n < 2; ++n)
                    acc[m][n] = __builtin_amdgcn_mfma_f32_16x16x32_bf16(
                        af[m], bfr[n], acc[m][n], 0, 0, 0);
        }
    }

#pragma unroll
    for (int m = 0; m < 2; ++m) {
#pragma unroll
        for (int n = 0; n < 2; ++n) {
            int gcol = bj + wn * 32 + n * 16 + l15;
            float bv = bias[gcol];
#pragma unroll
            for (int r = 0; r < 4; ++r) {
                int grow = bi + wm * 32 + m * 16 + lg * 4 + r;
                float v = acc[m][n][r] + bv;
                if (ACT) v = 0.5f * v * (1.0f + erff(v * 0.70710678118654752440f));
                if (OUTBF16)
                    ((__hip_bfloat16*)Cout)[(size_t)grow * N + gcol] = __float2bfloat16(v);
                else
                    ((float*)Cout)[(size_t)grow * N + gcol] = v;
            }
        }
    }
}

extern "C" void kernel_launch(void* const* d_in, const int* in_sizes, int n_in,
                              void* d_out, int out_size, void* d_ws, size_t ws_size,
                              hipStream_t stream)
{
    const float* x_in = (const float*)d_in[0];   // (18432,1024)
    const float* W1   = (const float*)d_in[1];   // (1024,4096)
    const float* b1   = (const float*)d_in[2];
    const float* W2   = (const float*)d_in[3];   // (4096,4096)
    const float* b2   = (const float*)d_in[4];
    float* out = (float*)d_out;                  // (512,4096) fp32

    // ---- workspace carve -----------------------------------------------------
    const size_t XBYTES = (size_t)9216 * 1024 * 4;   // 37.75 MB
    char* base = (char*)d_ws;
    float* xA     = (float*)base;
    float* xB     = (float*)(base + XBYTES);
    float* metric = (float*)(base + 2 * XBYTES);
    char*  tail   = base + 2 * XBYTES + (size_t)18432 * 64 * 4;
    float* sizeA  = (float*)tail;               tail += 9216 * 4;
    float* sizeB  = (float*)tail;               tail += 9216 * 4;
    float* nmax   = (float*)tail;               tail += 9216 * 4;
    int*   nidx   = (int*)tail;                 tail += 9216 * 4;
    int*   edgeidx= (int*)tail;                 tail += 2048;

    // bf16 overlays (live only after the merge rounds):
    //   xA (dead after rd4->rd5 read):  W2t (32 MB)
    //   xB (tokens use first 2 MB):     h_bf @+2MB, xbf @+6MB, W1t @+7MB
    __hip_bfloat16* W2t  = (__hip_bfloat16*)xA;
    __hip_bfloat16* h_bf = (__hip_bfloat16*)((char*)xB + (2u << 20));
    __hip_bfloat16* xbf  = (__hip_bfloat16*)((char*)xB + (6u << 20));
    __hip_bfloat16* W1t  = (__hip_bfloat16*)((char*)xB + (7u << 20));

    const int pcount[6] = {18432, 9216, 4608, 2304, 1152, 576};
    float* xbufs[2] = {xA, xB};
    float* sbufs[2] = {sizeA, sizeB};

    const float* xcur = x_in;
    const float* scur = nullptr;

    for (int rd = 0; rd < 6; ++rd) {
        int p  = pcount[rd];
        int P2 = p / 2;
        float* xout = xbufs[rd & 1];
        float* sout = sbufs[rd & 1];
        // pmax/pidx scratch in the region merge is ABOUT to overwrite (dead
        // before merge writes): pmax @ xout, pidx @ xout + 16 MB.
        float* pmax = xout;
        int*   pidx = (int*)((char*)xout + (16u << 20));

        metric_kernel<<<dim3((p + 3) / 4), dim3(256), 0, stream>>>(xcur, metric, p);

        int JB = (P2 + 63) / 64;
        scores_kernel<<<dim3(JB, JB), dim3(256), 0, stream>>>(metric, pmax, pidx, P2);
        reduce_kernel<<<dim3((P2 + 255) / 256), dim3(256), 0, stream>>>(
            pmax, pidx, nmax, nidx, P2, JB);

        if (rd < 5) {
            merge_kernel<<<dim3(P2), dim3(256), 0, stream>>>(xcur, scur, nidx, nmax,
                                                             xout, sout, P2);
        } else {
            rank_kernel<<<dim3(1), dim3(512), 0, stream>>>(nmax, edgeidx, P2);
            unm_kernel<<<dim3(P2 - 64), dim3(256), 0, stream>>>(xcur, scur, edgeidx,
                                                                xout, 64);
            dst6_kernel<<<dim3(P2), dim3(256), 0, stream>>>(xcur, scur, edgeidx, nidx,
                                                            xout, 64, P2 - 64);
        }
        xcur = xout;
        scur = sout;
    }

    // ---- bf16 casts ----------------------------------------------------------
    castx_kernel<<<dim3((512 * 1024 + 255) / 256), dim3(256), 0, stream>>>(
        xcur, xbf, 512 * 1024);
    transcast_kernel<<<dim3(4096 / 32, 1024 / 32), dim3(256), 0, stream>>>(
        W1, W1t, 1024, 4096);
    transcast_kernel<<<dim3(4096 / 32, 4096 / 32), dim3(256), 0, stream>>>(
        W2, W2t, 4096, 4096);

    // ---- MLP: h = gelu(x@W1+b1) [bf16]; out = h@W2+b2 [fp32] ----------------
    mfma_gemm_kernel<1, 1><<<dim3(4096 / 64, 512 / 64), dim3(256), 0, stream>>>(
        (const unsigned short*)xbf, (const unsigned short*)W1t, b1,
        (void*)h_bf, 512, 4096, 1024);
    mfma_gemm_kernel<0, 0><<<dim3(4096 / 64, 512 / 64), dim3(256), 0, stream>>>(
        (const unsigned short*)h_bf, (const unsigned short*)W2t, b2,
        (void*)out, 512, 4096, 4096);
}